// Round 1
// baseline (131.863 us; speedup 1.0000x reference)
//
#include <hip/hip_runtime.h>

#define BB 4
#define NN 8192
#define RI 4
#define THREADS 256
#define OPP_CHUNK 512                  // opponents staged in LDS per block
#define PB (NN / (THREADS * RI))       // 8 point-blocks
#define OC (NN / OPP_CHUNK)            // 16 opponent chunks

__global__ void cd_init_kernel(unsigned int* mins, int n) {
    int i = blockIdx.x * blockDim.x + threadIdx.x;
    if (i < n) mins[i] = 0x7F800000u;  // +inf
}

__global__ __launch_bounds__(THREADS) void cd_min_kernel(
    const float* __restrict__ pred, const float* __restrict__ gt,
    const float* __restrict__ coords,
    unsigned int* __restrict__ min1, unsigned int* __restrict__ min2)
{
    __shared__ float s[OPP_CHUNK * 3];  // packed xyzxyz...

    int bid = blockIdx.x;
    int oc  = bid % OC;        bid /= OC;
    int pb  = bid % PB;        bid /= PB;
    int b   = bid % BB;        bid /= BB;
    int dir = bid;             // 0: own=gt,opp=gen ; 1: own=gen,opp=gt

    const float* ownReg = dir ? pred : gt;
    const float* oppReg = dir ? gt : pred;
    unsigned int* target = dir ? min2 : min1;

    const float* cb = coords + b * 3 * NN;
    const float* ob = ownReg + b * 3 * NN;
    const float* qb = oppReg + b * 3 * NN;

    // stage opponent chunk into LDS (packed xyz; stride-3 writes are bank-conflict-free)
    int n0 = oc * OPP_CHUNK;
    for (int k = threadIdx.x; k < OPP_CHUNK; k += THREADS) {
        int n = n0 + k;
        s[k * 3 + 0] = cb[0 * NN + n] + qb[0 * NN + n];
        s[k * 3 + 1] = cb[1 * NN + n] + qb[1 * NN + n];
        s[k * 3 + 2] = cb[2 * NN + n] + qb[2 * NN + n];
    }

    // own points (RI per thread, strided for coalesced atomics)
    int p0 = pb * (THREADS * RI);
    float px[RI], py[RI], pz[RI], mn[RI];
    int idx[RI];
#pragma unroll
    for (int i = 0; i < RI; i++) {
        int n = p0 + threadIdx.x + i * THREADS;
        idx[i] = n;
        px[i] = cb[0 * NN + n] + ob[0 * NN + n];
        py[i] = cb[1 * NN + n] + ob[1 * NN + n];
        pz[i] = cb[2 * NN + n] + ob[2 * NN + n];
        mn[i] = 3.0e38f;
    }

    __syncthreads();

    // scan opponents: 4 points per step via 3 uniform-address float4 LDS reads
    for (int j = 0; j < OPP_CHUNK; j += 4) {
        float4 v0 = *(const float4*)&s[j * 3 + 0];
        float4 v1 = *(const float4*)&s[j * 3 + 4];
        float4 v2 = *(const float4*)&s[j * 3 + 8];
        float qx[4] = { v0.x, v0.w, v1.z, v2.y };
        float qy[4] = { v0.y, v1.x, v1.w, v2.z };
        float qz[4] = { v0.z, v1.y, v2.x, v2.w };
#pragma unroll
        for (int jj = 0; jj < 4; jj++) {
#pragma unroll
            for (int i = 0; i < RI; i++) {
                float dx = px[i] - qx[jj];
                float dy = py[i] - qy[jj];
                float dz = pz[i] - qz[jj];
                float d = fmaf(dx, dx, fmaf(dy, dy, dz * dz));
                mn[i] = fminf(mn[i], d);
            }
        }
    }

#pragma unroll
    for (int i = 0; i < RI; i++)
        atomicMin(&target[b * NN + idx[i]], __float_as_uint(mn[i]));
}

__global__ __launch_bounds__(256) void cd_reduce_kernel(const unsigned int* __restrict__ mins,
                                                        float* __restrict__ out)
{
    // deterministic single-block sum of 2*BB*NN mins
    float sum = 0.0f;
    for (int i = threadIdx.x; i < 2 * BB * NN; i += 256)
        sum += __uint_as_float(mins[i]);
#pragma unroll
    for (int off = 32; off > 0; off >>= 1)
        sum += __shfl_down(sum, off, 64);
    __shared__ float wsum[4];
    int wave = threadIdx.x >> 6;
    if ((threadIdx.x & 63) == 0) wsum[wave] = sum;
    __syncthreads();
    if (threadIdx.x == 0) {
        float t = wsum[0] + wsum[1] + wsum[2] + wsum[3];
        out[0] = t / (float)BB;
    }
}

extern "C" void kernel_launch(void* const* d_in, const int* in_sizes, int n_in,
                              void* d_out, int out_size, void* d_ws, size_t ws_size,
                              hipStream_t stream) {
    const float* pred   = (const float*)d_in[0];
    const float* gt     = (const float*)d_in[1];
    const float* coords = (const float*)d_in[2];
    float* out = (float*)d_out;

    unsigned int* mins = (unsigned int*)d_ws;       // min1[BB*NN] then min2[BB*NN]
    unsigned int* min1 = mins;
    unsigned int* min2 = mins + BB * NN;

    int total_mins = 2 * BB * NN;
    hipLaunchKernelGGL(cd_init_kernel, dim3((total_mins + 255) / 256), dim3(256), 0, stream,
                       mins, total_mins);

    int nblocks = 2 * BB * PB * OC;  // 1024
    hipLaunchKernelGGL(cd_min_kernel, dim3(nblocks), dim3(THREADS), 0, stream,
                       pred, gt, coords, min1, min2);

    hipLaunchKernelGGL(cd_reduce_kernel, dim3(1), dim3(256), 0, stream, mins, out);
}

// Round 3
// 60.304 us; speedup vs baseline: 2.1866x; 2.1866x over previous
//
#include <hip/hip_runtime.h>

typedef float v2f __attribute__((ext_vector_type(2)));

#define BB 4
#define NN 8192
#define RI 8                           // own points per thread (4 packed pairs)
#define THREADS 256
#define OPP_CHUNK 512                  // opponents staged in LDS per block
#define PB (NN / (THREADS * RI))       // 4 point-blocks
#define OC (NN / OPP_CHUNK)            // 16 opponent chunks

// d = a * {b.lo,b.lo} + {c.hi,c.hi}
__device__ inline v2f pk_fma_blo_chi(v2f a, v2f b, v2f c) {
    v2f d;
    asm("v_pk_fma_f32 %0, %1, %2, %3 op_sel:[0,0,1] op_sel_hi:[1,0,1]"
        : "=v"(d) : "v"(a), "v"(b), "v"(c));
    return d;
}
// d = a * {b.hi,b.hi} + c
__device__ inline v2f pk_fma_bhi(v2f a, v2f b, v2f c) {
    v2f d;
    asm("v_pk_fma_f32 %0, %1, %2, %3 op_sel:[0,1,0] op_sel_hi:[1,1,1]"
        : "=v"(d) : "v"(a), "v"(b), "v"(c));
    return d;
}
// d = a * {b.lo,b.lo} + c
__device__ inline v2f pk_fma_blo(v2f a, v2f b, v2f c) {
    v2f d;
    asm("v_pk_fma_f32 %0, %1, %2, %3 op_sel:[0,0,0] op_sel_hi:[1,0,1]"
        : "=v"(d) : "v"(a), "v"(b), "v"(c));
    return d;
}

__global__ void cd_init_kernel(unsigned int* mins, int n) {
    int i = blockIdx.x * blockDim.x + threadIdx.x;
    if (i < n) mins[i] = 0x7F800000u;  // +inf
}

__global__ __launch_bounds__(THREADS) void cd_min_kernel(
    const float* __restrict__ pred, const float* __restrict__ gt,
    const float* __restrict__ coords,
    unsigned int* __restrict__ min1, unsigned int* __restrict__ min2)
{
    __shared__ float4 s4[OPP_CHUNK];   // (x, y, z, -0.5*|q|^2)

    int bid = blockIdx.x;
    int oc  = bid % OC;        bid /= OC;
    int pb  = bid % PB;        bid /= PB;
    int b   = bid % BB;        bid /= BB;
    int dir = bid;             // 0: own=gt,opp=gen ; 1: own=gen,opp=gt

    const float* ownReg = dir ? pred : gt;
    const float* oppReg = dir ? gt : pred;
    unsigned int* target = dir ? min2 : min1;

    const float* cb = coords + b * 3 * NN;
    const float* ob = ownReg + b * 3 * NN;
    const float* qb = oppReg + b * 3 * NN;

    // stage opponent chunk into LDS as float4 (x,y,z,w=-0.5|q|^2)
    int n0 = oc * OPP_CHUNK;
    for (int k = threadIdx.x; k < OPP_CHUNK; k += THREADS) {
        int n = n0 + k;
        float x = cb[0 * NN + n] + qb[0 * NN + n];
        float y = cb[1 * NN + n] + qb[1 * NN + n];
        float z = cb[2 * NN + n] + qb[2 * NN + n];
        float w = -0.5f * (x * x + y * y + z * z);
        s4[k] = make_float4(x, y, z, w);
    }

    // own points, packed 2 per VGPR pair
    int p0 = pb * (THREADS * RI);
    v2f px[RI / 2], py[RI / 2], pz[RI / 2], mx[RI / 2];
#pragma unroll
    for (int i = 0; i < RI / 2; i++) {
#pragma unroll
        for (int h = 0; h < 2; h++) {
            int n = p0 + threadIdx.x + (2 * i + h) * THREADS;
            px[i][h] = cb[0 * NN + n] + ob[0 * NN + n];
            py[i][h] = cb[1 * NN + n] + ob[1 * NN + n];
            pz[i][h] = cb[2 * NN + n] + ob[2 * NN + n];
            mx[i][h] = -3.0e38f;
        }
    }

    __syncthreads();

    // scan opponents: score = p.q - 0.5|q|^2 ; track max score per own point
    const v2f* s2 = (const v2f*)s4;
#pragma unroll 2
    for (int j = 0; j < OPP_CHUNK; j++) {
        v2f qxy = s2[2 * j + 0];       // {x, y}
        v2f qzw = s2[2 * j + 1];       // {z, w}
#pragma unroll
        for (int i = 0; i < RI / 2; i++) {
            v2f t = pk_fma_blo_chi(pz[i], qzw, qzw);  // pz*z + w
            t = pk_fma_bhi(py[i], qxy, t);            // + py*y
            t = pk_fma_blo(px[i], qxy, t);            // + px*x
            mx[i].x = fmaxf(mx[i].x, t.x);
            mx[i].y = fmaxf(mx[i].y, t.y);
        }
    }

    // epilogue: d = |p|^2 - 2*maxscore (clamped at 0), atomicMin as uint
#pragma unroll
    for (int i = 0; i < RI / 2; i++) {
#pragma unroll
        for (int h = 0; h < 2; h++) {
            float x = px[i][h], y = py[i][h], z = pz[i][h], m = mx[i][h];
            float pp = fmaf(x, x, fmaf(y, y, z * z));
            float d = fmaxf(fmaf(-2.0f, m, pp), 0.0f);
            int n = p0 + threadIdx.x + (2 * i + h) * THREADS;
            atomicMin(&target[b * NN + n], __float_as_uint(d));
        }
    }
}

__global__ __launch_bounds__(256) void cd_reduceA(const unsigned int* __restrict__ mins,
                                                  float* __restrict__ partial)
{
    int base = blockIdx.x * 1024;
    float s = 0.0f;
    for (int i = threadIdx.x; i < 1024; i += 256)
        s += __uint_as_float(mins[base + i]);
#pragma unroll
    for (int off = 32; off > 0; off >>= 1)
        s += __shfl_down(s, off, 64);
    __shared__ float wsum[4];
    int wave = threadIdx.x >> 6;
    if ((threadIdx.x & 63) == 0) wsum[wave] = s;
    __syncthreads();
    if (threadIdx.x == 0)
        partial[blockIdx.x] = wsum[0] + wsum[1] + wsum[2] + wsum[3];
}

__global__ __launch_bounds__(64) void cd_reduceB(const float* __restrict__ partial,
                                                 float* __restrict__ out)
{
    float s = partial[threadIdx.x];   // 64 partials, one wave
#pragma unroll
    for (int off = 32; off > 0; off >>= 1)
        s += __shfl_down(s, off, 64);
    if (threadIdx.x == 0) out[0] = s / (float)BB;
}

extern "C" void kernel_launch(void* const* d_in, const int* in_sizes, int n_in,
                              void* d_out, int out_size, void* d_ws, size_t ws_size,
                              hipStream_t stream) {
    const float* pred   = (const float*)d_in[0];
    const float* gt     = (const float*)d_in[1];
    const float* coords = (const float*)d_in[2];
    float* out = (float*)d_out;

    unsigned int* mins = (unsigned int*)d_ws;       // min1[BB*NN] then min2[BB*NN]
    unsigned int* min1 = mins;
    unsigned int* min2 = mins + BB * NN;
    float* partial = (float*)(mins + 2 * BB * NN);  // 64 floats

    int total_mins = 2 * BB * NN;                   // 65536
    hipLaunchKernelGGL(cd_init_kernel, dim3((total_mins + 255) / 256), dim3(256), 0, stream,
                       mins, total_mins);

    int nblocks = 2 * BB * PB * OC;                 // 512
    hipLaunchKernelGGL(cd_min_kernel, dim3(nblocks), dim3(THREADS), 0, stream,
                       pred, gt, coords, min1, min2);

    hipLaunchKernelGGL(cd_reduceA, dim3(total_mins / 1024), dim3(256), 0, stream,
                       mins, partial);
    hipLaunchKernelGGL(cd_reduceB, dim3(1), dim3(64), 0, stream, partial, out);
}

// Round 4
// 55.056 us; speedup vs baseline: 2.3951x; 1.0953x over previous
//
#include <hip/hip_runtime.h>

typedef float v2f __attribute__((ext_vector_type(2)));

#define BB 4
#define NN 8192
#define RI 8                           // own points per thread (4 packed pairs)
#define THREADS 256
#define OPP_CHUNK 256                  // opponents staged in LDS per block
#define PB (NN / (THREADS * RI))       // 4 point-blocks
#define OC (NN / OPP_CHUNK)            // 32 opponent chunks

// d = a * {b.lo,b.lo} + {c.hi,c.hi}
__device__ inline v2f pk_fma_blo_chi(v2f a, v2f b, v2f c) {
    v2f d;
    asm("v_pk_fma_f32 %0, %1, %2, %3 op_sel:[0,0,1] op_sel_hi:[1,0,1]"
        : "=v"(d) : "v"(a), "v"(b), "v"(c));
    return d;
}
// d = a * {b.hi,b.hi} + c
__device__ inline v2f pk_fma_bhi(v2f a, v2f b, v2f c) {
    v2f d;
    asm("v_pk_fma_f32 %0, %1, %2, %3 op_sel:[0,1,0] op_sel_hi:[1,1,1]"
        : "=v"(d) : "v"(a), "v"(b), "v"(c));
    return d;
}
// d = a * {b.lo,b.lo} + c
__device__ inline v2f pk_fma_blo(v2f a, v2f b, v2f c) {
    v2f d;
    asm("v_pk_fma_f32 %0, %1, %2, %3 op_sel:[0,0,0] op_sel_hi:[1,0,1]"
        : "=v"(d) : "v"(a), "v"(b), "v"(c));
    return d;
}

__global__ void cd_init_kernel(unsigned int* mins, int n) {
    int i = blockIdx.x * blockDim.x + threadIdx.x;
    if (i < n) mins[i] = 0x7F800000u;  // +inf
}

__global__ __launch_bounds__(THREADS) void cd_min_kernel(
    const float* __restrict__ pred, const float* __restrict__ gt,
    const float* __restrict__ coords,
    unsigned int* __restrict__ min1, unsigned int* __restrict__ min2)
{
    __shared__ float4 s4[OPP_CHUNK];   // (x, y, z, -0.5*|q|^2)

    int bid = blockIdx.x;
    int oc  = bid % OC;        bid /= OC;
    int pb  = bid % PB;        bid /= PB;
    int b   = bid % BB;        bid /= BB;
    int dir = bid;             // 0: own=gt,opp=gen ; 1: own=gen,opp=gt

    const float* ownReg = dir ? pred : gt;
    const float* oppReg = dir ? gt : pred;
    unsigned int* target = dir ? min2 : min1;

    const float* cb = coords + b * 3 * NN;
    const float* ob = ownReg + b * 3 * NN;
    const float* qb = oppReg + b * 3 * NN;

    // stage opponent chunk into LDS as float4 (x,y,z,w=-0.5|q|^2)
    int n0 = oc * OPP_CHUNK;
    for (int k = threadIdx.x; k < OPP_CHUNK; k += THREADS) {
        int n = n0 + k;
        float x = cb[0 * NN + n] + qb[0 * NN + n];
        float y = cb[1 * NN + n] + qb[1 * NN + n];
        float z = cb[2 * NN + n] + qb[2 * NN + n];
        float w = -0.5f * (x * x + y * y + z * z);
        s4[k] = make_float4(x, y, z, w);
    }

    // own points, packed 2 per VGPR pair
    int p0 = pb * (THREADS * RI);
    v2f px[RI / 2], py[RI / 2], pz[RI / 2], mx[RI / 2];
#pragma unroll
    for (int i = 0; i < RI / 2; i++) {
#pragma unroll
        for (int h = 0; h < 2; h++) {
            int n = p0 + threadIdx.x + (2 * i + h) * THREADS;
            px[i][h] = cb[0 * NN + n] + ob[0 * NN + n];
            py[i][h] = cb[1 * NN + n] + ob[1 * NN + n];
            pz[i][h] = cb[2 * NN + n] + ob[2 * NN + n];
            mx[i][h] = -3.0e38f;
        }
    }

    __syncthreads();

    // scan opponents: score = p.q - 0.5|q|^2 ; track max score per own point.
    // 4 opponents per step, next 4 prefetched from LDS during compute.
    const v2f* s2 = (const v2f*)s4;

#define COMP(QXY, QZW) do {                                      \
    _Pragma("unroll")                                            \
    for (int i = 0; i < RI / 2; i++) {                           \
        v2f t = pk_fma_blo_chi(pz[i], (QZW), (QZW));             \
        t = pk_fma_bhi(py[i], (QXY), t);                         \
        t = pk_fma_blo(px[i], (QXY), t);                         \
        mx[i].x = fmaxf(mx[i].x, t.x);                           \
        mx[i].y = fmaxf(mx[i].y, t.y);                           \
    } } while (0)

    v2f cxy0 = s2[0], czw0 = s2[1];
    v2f cxy1 = s2[2], czw1 = s2[3];
    v2f cxy2 = s2[4], czw2 = s2[5];
    v2f cxy3 = s2[6], czw3 = s2[7];
    for (int j = 0; j < OPP_CHUNK - 4; j += 4) {
        v2f nxy0 = s2[2 * j +  8], nzw0 = s2[2 * j +  9];
        v2f nxy1 = s2[2 * j + 10], nzw1 = s2[2 * j + 11];
        v2f nxy2 = s2[2 * j + 12], nzw2 = s2[2 * j + 13];
        v2f nxy3 = s2[2 * j + 14], nzw3 = s2[2 * j + 15];
        COMP(cxy0, czw0);
        COMP(cxy1, czw1);
        COMP(cxy2, czw2);
        COMP(cxy3, czw3);
        cxy0 = nxy0; czw0 = nzw0;
        cxy1 = nxy1; czw1 = nzw1;
        cxy2 = nxy2; czw2 = nzw2;
        cxy3 = nxy3; czw3 = nzw3;
    }
    COMP(cxy0, czw0);
    COMP(cxy1, czw1);
    COMP(cxy2, czw2);
    COMP(cxy3, czw3);
#undef COMP

    // epilogue: d = |p|^2 - 2*maxscore (clamped at 0), atomicMin as uint
#pragma unroll
    for (int i = 0; i < RI / 2; i++) {
#pragma unroll
        for (int h = 0; h < 2; h++) {
            float x = px[i][h], y = py[i][h], z = pz[i][h], m = mx[i][h];
            float pp = fmaf(x, x, fmaf(y, y, z * z));
            float d = fmaxf(fmaf(-2.0f, m, pp), 0.0f);
            int n = p0 + threadIdx.x + (2 * i + h) * THREADS;
            atomicMin(&target[b * NN + n], __float_as_uint(d));
        }
    }
}

__global__ __launch_bounds__(256) void cd_reduceA(const unsigned int* __restrict__ mins,
                                                  float* __restrict__ partial)
{
    int base = blockIdx.x * 1024;
    float s = 0.0f;
    for (int i = threadIdx.x; i < 1024; i += 256)
        s += __uint_as_float(mins[base + i]);
#pragma unroll
    for (int off = 32; off > 0; off >>= 1)
        s += __shfl_down(s, off, 64);
    __shared__ float wsum[4];
    int wave = threadIdx.x >> 6;
    if ((threadIdx.x & 63) == 0) wsum[wave] = s;
    __syncthreads();
    if (threadIdx.x == 0)
        partial[blockIdx.x] = wsum[0] + wsum[1] + wsum[2] + wsum[3];
}

__global__ __launch_bounds__(64) void cd_reduceB(const float* __restrict__ partial,
                                                 float* __restrict__ out)
{
    float s = partial[threadIdx.x];   // 64 partials, one wave
#pragma unroll
    for (int off = 32; off > 0; off >>= 1)
        s += __shfl_down(s, off, 64);
    if (threadIdx.x == 0) out[0] = s / (float)BB;
}

extern "C" void kernel_launch(void* const* d_in, const int* in_sizes, int n_in,
                              void* d_out, int out_size, void* d_ws, size_t ws_size,
                              hipStream_t stream) {
    const float* pred   = (const float*)d_in[0];
    const float* gt     = (const float*)d_in[1];
    const float* coords = (const float*)d_in[2];
    float* out = (float*)d_out;

    unsigned int* mins = (unsigned int*)d_ws;       // min1[BB*NN] then min2[BB*NN]
    unsigned int* min1 = mins;
    unsigned int* min2 = mins + BB * NN;
    float* partial = (float*)(mins + 2 * BB * NN);  // 64 floats

    int total_mins = 2 * BB * NN;                   // 65536
    hipLaunchKernelGGL(cd_init_kernel, dim3((total_mins + 255) / 256), dim3(256), 0, stream,
                       mins, total_mins);

    int nblocks = 2 * BB * PB * OC;                 // 1024
    hipLaunchKernelGGL(cd_min_kernel, dim3(nblocks), dim3(THREADS), 0, stream,
                       pred, gt, coords, min1, min2);

    hipLaunchKernelGGL(cd_reduceA, dim3(total_mins / 1024), dim3(256), 0, stream,
                       mins, partial);
    hipLaunchKernelGGL(cd_reduceB, dim3(1), dim3(64), 0, stream, partial, out);
}

// Round 5
// 53.707 us; speedup vs baseline: 2.4552x; 1.0251x over previous
//
#include <hip/hip_runtime.h>

typedef float v2f __attribute__((ext_vector_type(2)));

#define BB 4
#define NN 8192
#define RI 4                           // own points per thread (2 packed pairs)
#define THREADS 256
#define OPP_CHUNK 256                  // opponents staged in LDS per block
#define PB (NN / (THREADS * RI))       // 8 point-blocks
#define OC (NN / OPP_CHUNK)            // 32 opponent chunks

// d = a * {b.lo,b.lo} + {c.hi,c.hi}
__device__ inline v2f pk_fma_blo_chi(v2f a, v2f b, v2f c) {
    v2f d;
    asm("v_pk_fma_f32 %0, %1, %2, %3 op_sel:[0,0,1] op_sel_hi:[1,0,1]"
        : "=v"(d) : "v"(a), "v"(b), "v"(c));
    return d;
}
// d = a * {b.hi,b.hi} + c
__device__ inline v2f pk_fma_bhi(v2f a, v2f b, v2f c) {
    v2f d;
    asm("v_pk_fma_f32 %0, %1, %2, %3 op_sel:[0,1,0] op_sel_hi:[1,1,1]"
        : "=v"(d) : "v"(a), "v"(b), "v"(c));
    return d;
}
// d = a * {b.lo,b.lo} + c
__device__ inline v2f pk_fma_blo(v2f a, v2f b, v2f c) {
    v2f d;
    asm("v_pk_fma_f32 %0, %1, %2, %3 op_sel:[0,0,0] op_sel_hi:[1,0,1]"
        : "=v"(d) : "v"(a), "v"(b), "v"(c));
    return d;
}

__device__ inline float max3f(float a, float b, float c) {
    float d;
    asm("v_max3_f32 %0, %1, %2, %3" : "=v"(d) : "v"(a), "v"(b), "v"(c));
    return d;
}

// score = p.q - 0.5|q|^2 for 2 packed own points vs one opponent (qxy={x,y}, qzw={z,w})
__device__ inline v2f dotw(v2f px, v2f py, v2f pz, v2f qxy, v2f qzw) {
    v2f t = pk_fma_blo_chi(pz, qzw, qzw);  // pz*z + w
    t = pk_fma_bhi(py, qxy, t);            // + py*y
    t = pk_fma_blo(px, qxy, t);            // + px*x
    return t;
}

__global__ void cd_init_kernel(unsigned int* mins, int n) {
    int i = blockIdx.x * blockDim.x + threadIdx.x;
    if (i < n) mins[i] = 0x7F800000u;  // +inf
}

__global__ __launch_bounds__(THREADS) void cd_min_kernel(
    const float* __restrict__ pred, const float* __restrict__ gt,
    const float* __restrict__ coords,
    unsigned int* __restrict__ min1, unsigned int* __restrict__ min2)
{
    __shared__ float4 s4[OPP_CHUNK];   // (x, y, z, -0.5*|q|^2)

    int bid = blockIdx.x;
    int oc  = bid % OC;        bid /= OC;
    int pb  = bid % PB;        bid /= PB;
    int b   = bid % BB;        bid /= BB;
    int dir = bid;             // 0: own=gt,opp=gen ; 1: own=gen,opp=gt

    const float* ownReg = dir ? pred : gt;
    const float* oppReg = dir ? gt : pred;
    unsigned int* target = dir ? min2 : min1;

    const float* cb = coords + b * 3 * NN;
    const float* ob = ownReg + b * 3 * NN;
    const float* qb = oppReg + b * 3 * NN;

    // stage opponent chunk into LDS (THREADS == OPP_CHUNK: one point per thread)
    {
        int n = oc * OPP_CHUNK + threadIdx.x;
        float x = cb[0 * NN + n] + qb[0 * NN + n];
        float y = cb[1 * NN + n] + qb[1 * NN + n];
        float z = cb[2 * NN + n] + qb[2 * NN + n];
        float w = -0.5f * (x * x + y * y + z * z);
        s4[threadIdx.x] = make_float4(x, y, z, w);
    }

    // own points, packed 2 per VGPR pair
    int p0 = pb * (THREADS * RI);
    v2f px[RI / 2], py[RI / 2], pz[RI / 2], mx[RI / 2];
#pragma unroll
    for (int i = 0; i < RI / 2; i++) {
#pragma unroll
        for (int h = 0; h < 2; h++) {
            int n = p0 + threadIdx.x + (2 * i + h) * THREADS;
            px[i][h] = cb[0 * NN + n] + ob[0 * NN + n];
            py[i][h] = cb[1 * NN + n] + ob[1 * NN + n];
            pz[i][h] = cb[2 * NN + n] + ob[2 * NN + n];
            mx[i][h] = -3.0e38f;
        }
    }

    __syncthreads();

    // scan opponents 8 at a time, register-double-buffered (fresh loads, no movs)
    const v2f* s2 = (const v2f*)s4;

#define COMP4(XY0,ZW0,XY1,ZW1,XY2,ZW2,XY3,ZW3) do {                \
    _Pragma("unroll")                                              \
    for (int i = 0; i < RI / 2; i++) {                             \
        v2f t0 = dotw(px[i], py[i], pz[i], XY0, ZW0);              \
        v2f t1 = dotw(px[i], py[i], pz[i], XY1, ZW1);              \
        v2f t2 = dotw(px[i], py[i], pz[i], XY2, ZW2);              \
        v2f t3 = dotw(px[i], py[i], pz[i], XY3, ZW3);              \
        mx[i].x = max3f(mx[i].x, t0.x, t1.x);                      \
        mx[i].y = max3f(mx[i].y, t0.y, t1.y);                      \
        mx[i].x = max3f(mx[i].x, t2.x, t3.x);                      \
        mx[i].y = max3f(mx[i].y, t2.y, t3.y);                      \
    } } while (0)

    v2f a0 = s2[0], b0 = s2[1], a1 = s2[2], b1 = s2[3];
    v2f a2 = s2[4], b2 = s2[5], a3 = s2[6], b3 = s2[7];
    int j = 0;
    for (;;) {
        v2f c0 = s2[2*(j+4)], d0 = s2[2*(j+4)+1];
        v2f c1 = s2[2*(j+5)], d1 = s2[2*(j+5)+1];
        v2f c2 = s2[2*(j+6)], d2 = s2[2*(j+6)+1];
        v2f c3 = s2[2*(j+7)], d3 = s2[2*(j+7)+1];
        COMP4(a0,b0, a1,b1, a2,b2, a3,b3);
        j += 8;
        if (j >= OPP_CHUNK) { COMP4(c0,d0, c1,d1, c2,d2, c3,d3); break; }
        a0 = s2[2*j],     b0 = s2[2*j+1];
        a1 = s2[2*(j+1)], b1 = s2[2*(j+1)+1];
        a2 = s2[2*(j+2)], b2 = s2[2*(j+2)+1];
        a3 = s2[2*(j+3)], b3 = s2[2*(j+3)+1];
        COMP4(c0,d0, c1,d1, c2,d2, c3,d3);
    }
#undef COMP4

    // epilogue: d = |p|^2 - 2*maxscore (clamped at 0), atomicMin as uint
#pragma unroll
    for (int i = 0; i < RI / 2; i++) {
#pragma unroll
        for (int h = 0; h < 2; h++) {
            float x = px[i][h], y = py[i][h], z = pz[i][h], m = mx[i][h];
            float pp = fmaf(x, x, fmaf(y, y, z * z));
            float d = fmaxf(fmaf(-2.0f, m, pp), 0.0f);
            int n = p0 + threadIdx.x + (2 * i + h) * THREADS;
            atomicMin(&target[b * NN + n], __float_as_uint(d));
        }
    }
}

__global__ __launch_bounds__(256) void cd_reduceA(const unsigned int* __restrict__ mins,
                                                  float* __restrict__ partial)
{
    int base = blockIdx.x * 1024;
    float s = 0.0f;
    for (int i = threadIdx.x; i < 1024; i += 256)
        s += __uint_as_float(mins[base + i]);
#pragma unroll
    for (int off = 32; off > 0; off >>= 1)
        s += __shfl_down(s, off, 64);
    __shared__ float wsum[4];
    int wave = threadIdx.x >> 6;
    if ((threadIdx.x & 63) == 0) wsum[wave] = s;
    __syncthreads();
    if (threadIdx.x == 0)
        partial[blockIdx.x] = wsum[0] + wsum[1] + wsum[2] + wsum[3];
}

__global__ __launch_bounds__(64) void cd_reduceB(const float* __restrict__ partial,
                                                 float* __restrict__ out)
{
    float s = partial[threadIdx.x];   // 64 partials, one wave
#pragma unroll
    for (int off = 32; off > 0; off >>= 1)
        s += __shfl_down(s, off, 64);
    if (threadIdx.x == 0) out[0] = s / (float)BB;
}

extern "C" void kernel_launch(void* const* d_in, const int* in_sizes, int n_in,
                              void* d_out, int out_size, void* d_ws, size_t ws_size,
                              hipStream_t stream) {
    const float* pred   = (const float*)d_in[0];
    const float* gt     = (const float*)d_in[1];
    const float* coords = (const float*)d_in[2];
    float* out = (float*)d_out;

    unsigned int* mins = (unsigned int*)d_ws;       // min1[BB*NN] then min2[BB*NN]
    unsigned int* min1 = mins;
    unsigned int* min2 = mins + BB * NN;
    float* partial = (float*)(mins + 2 * BB * NN);  // 64 floats

    int total_mins = 2 * BB * NN;                   // 65536
    hipLaunchKernelGGL(cd_init_kernel, dim3((total_mins + 255) / 256), dim3(256), 0, stream,
                       mins, total_mins);

    int nblocks = 2 * BB * PB * OC;                 // 2048
    hipLaunchKernelGGL(cd_min_kernel, dim3(nblocks), dim3(THREADS), 0, stream,
                       pred, gt, coords, min1, min2);

    hipLaunchKernelGGL(cd_reduceA, dim3(total_mins / 1024), dim3(256), 0, stream,
                       mins, partial);
    hipLaunchKernelGGL(cd_reduceB, dim3(1), dim3(64), 0, stream, partial, out);
}

// Round 6
// 46.472 us; speedup vs baseline: 2.8375x; 1.1557x over previous
//
#include <hip/hip_runtime.h>

#define BB 4
#define NN 8192
#define RI 8                   // rows per thread
#define THREADS 256
#define ROWB (THREADS * RI)    // 2048 rows per block
#define PB (NN / ROWB)         // 4 row-blocks
#define COLB 128               // cols per block
#define NCB (NN / COLB)        // 64 col-blocks
#define CHUNK 64               // cols staged in LDS per iteration

__global__ void cd_init_kernel(unsigned int* mins, int n) {
    int i = blockIdx.x * blockDim.x + threadIdx.x;
    if (i < n) mins[i] = 0x7F800000u;  // +inf
}

// One pass over the distance matrix serving BOTH directions.
// u = p.q - 0.5|p|^2 - 0.5|q|^2 = -0.5 * d^2  (u <= 0)
// row-min d^2 <-> row-max u (registers); col-min d^2 <-> col-max u (LDS).
// float-max over non-positive floats == uint-min over bit patterns (exact).
__global__ __launch_bounds__(THREADS) void cd_both_kernel(
    const float* __restrict__ pred, const float* __restrict__ gt,
    const float* __restrict__ coords,
    unsigned int* __restrict__ min1, unsigned int* __restrict__ min2)
{
    __shared__ float4 s4[CHUNK];          // (x, y, z, -0.5|q|^2) per col
    __shared__ unsigned int colm[COLB];   // bit pattern of col-max u

    int bid = blockIdx.x;
    int cb = bid % NCB;   bid /= NCB;
    int pb = bid % PB;    bid /= PB;
    int b  = bid;

    const float* cbase = coords + b * 3 * NN;
    const float* gbase = gt   + b * 3 * NN;   // rows: gt points  -> min1
    const float* pbase = pred + b * 3 * NN;   // cols: gen points -> min2

    for (int i = threadIdx.x; i < COLB; i += THREADS)
        colm[i] = 0xFF800000u;                // -inf bits (uint-min identity)

    // rows into registers
    int r0 = pb * ROWB;
    float px[RI], py[RI], pz[RI], wp[RI], rm[RI];
#pragma unroll
    for (int i = 0; i < RI; i++) {
        int n = r0 + threadIdx.x + i * THREADS;
        float x = cbase[0 * NN + n] + gbase[0 * NN + n];
        float y = cbase[1 * NN + n] + gbase[1 * NN + n];
        float z = cbase[2 * NN + n] + gbase[2 * NN + n];
        px[i] = x; py[i] = y; pz[i] = z;
        wp[i] = -0.5f * (x * x + fmaf(y, y, z * z));
        rm[i] = -3.0e38f;
    }

    // lane-staggered column order; extra per-wave rotation to spread LDS atomics
    int lane = (threadIdx.x & 63) + (threadIdx.x >> 6) * 16;

    for (int ch = 0; ch < COLB / CHUNK; ++ch) {
        __syncthreads();      // previous chunk's readers done before restage
        if (threadIdx.x < CHUNK) {
            int n = cb * COLB + ch * CHUNK + threadIdx.x;
            float x = cbase[0 * NN + n] + pbase[0 * NN + n];
            float y = cbase[1 * NN + n] + pbase[1 * NN + n];
            float z = cbase[2 * NN + n] + pbase[2 * NN + n];
            float w = -0.5f * (x * x + fmaf(y, y, z * z));
            s4[threadIdx.x] = make_float4(x, y, z, w);
        }
        __syncthreads();

#pragma unroll 4
        for (int k = 0; k < CHUNK; ++k) {
            int c = (lane + k) & (CHUNK - 1);
            float4 q = s4[c];
            float u[RI];
#pragma unroll
            for (int i = 0; i < RI; i++) {
                float t = fmaf(pz[i], q.z, q.w);
                t = fmaf(py[i], q.y, t);
                t = fmaf(px[i], q.x, t);
                u[i] = t + wp[i];
                rm[i] = fmaxf(rm[i], u[i]);
            }
            // fold 8 u's into one col partial (tree; compiler forms v_max3)
            float a0 = fmaxf(fmaxf(u[0], u[1]), fmaxf(u[2], u[3]));
            float a1 = fmaxf(fmaxf(u[4], u[5]), fmaxf(u[6], u[7]));
            float um = fmaxf(a0, a1);
            atomicMin(&colm[ch * CHUNK + c], __float_as_uint(um));
        }
    }

    // row epilogue: d^2 = -2*max(u), clamp >= 0
#pragma unroll
    for (int i = 0; i < RI; i++) {
        float d = fmaxf(-2.0f * rm[i], 0.0f);
        int n = r0 + threadIdx.x + i * THREADS;
        atomicMin(&min1[b * NN + n], __float_as_uint(d));
    }

    __syncthreads();   // all ds_min done before reading colm
    for (int i = threadIdx.x; i < COLB; i += THREADS) {
        float uu = __uint_as_float(colm[i]);
        float d = fmaxf(-2.0f * uu, 0.0f);
        atomicMin(&min2[b * NN + cb * COLB + i], __float_as_uint(d));
    }
}

__global__ __launch_bounds__(256) void cd_reduceA(const unsigned int* __restrict__ mins,
                                                  float* __restrict__ partial)
{
    int base = blockIdx.x * 1024;
    float s = 0.0f;
    for (int i = threadIdx.x; i < 1024; i += 256)
        s += __uint_as_float(mins[base + i]);
#pragma unroll
    for (int off = 32; off > 0; off >>= 1)
        s += __shfl_down(s, off, 64);
    __shared__ float wsum[4];
    int wave = threadIdx.x >> 6;
    if ((threadIdx.x & 63) == 0) wsum[wave] = s;
    __syncthreads();
    if (threadIdx.x == 0)
        partial[blockIdx.x] = wsum[0] + wsum[1] + wsum[2] + wsum[3];
}

__global__ __launch_bounds__(64) void cd_reduceB(const float* __restrict__ partial,
                                                 float* __restrict__ out)
{
    float s = partial[threadIdx.x];   // 64 partials, one wave
#pragma unroll
    for (int off = 32; off > 0; off >>= 1)
        s += __shfl_down(s, off, 64);
    if (threadIdx.x == 0) out[0] = s / (float)BB;
}

extern "C" void kernel_launch(void* const* d_in, const int* in_sizes, int n_in,
                              void* d_out, int out_size, void* d_ws, size_t ws_size,
                              hipStream_t stream) {
    const float* pred   = (const float*)d_in[0];
    const float* gt     = (const float*)d_in[1];
    const float* coords = (const float*)d_in[2];
    float* out = (float*)d_out;

    unsigned int* mins = (unsigned int*)d_ws;       // min1[BB*NN] then min2[BB*NN]
    unsigned int* min1 = mins;
    unsigned int* min2 = mins + BB * NN;
    float* partial = (float*)(mins + 2 * BB * NN);  // 64 floats

    int total_mins = 2 * BB * NN;                   // 65536
    hipLaunchKernelGGL(cd_init_kernel, dim3((total_mins + 255) / 256), dim3(256), 0, stream,
                       mins, total_mins);

    int nblocks = BB * PB * NCB;                    // 1024
    hipLaunchKernelGGL(cd_both_kernel, dim3(nblocks), dim3(THREADS), 0, stream,
                       pred, gt, coords, min1, min2);

    hipLaunchKernelGGL(cd_reduceA, dim3(total_mins / 1024), dim3(256), 0, stream,
                       mins, partial);
    hipLaunchKernelGGL(cd_reduceB, dim3(1), dim3(64), 0, stream, partial, out);
}

// Round 8
// 44.725 us; speedup vs baseline: 2.9483x; 1.0390x over previous
//
#include <hip/hip_runtime.h>

#define BB 4
#define NN 8192
#define RI 8                   // rows per thread
#define THREADS 256
#define ROWB (THREADS * RI)    // 2048 rows per block
#define PB (NN / ROWB)         // 4 row-blocks
#define COLB 128               // cols per block (staged once)
#define NCB (NN / COLB)        // 64 col-blocks

__device__ inline float max3f(float a, float b, float c) {
    float d;
    asm("v_max3_f32 %0, %1, %2, %3" : "=v"(d) : "v"(a), "v"(b), "v"(c));
    return d;
}

__global__ void cd_init_kernel(unsigned int* mins, int n) {
    int i = blockIdx.x * blockDim.x + threadIdx.x;
    if (i < n) mins[i] = 0x7F800000u;  // +inf
}

// u = p.q - 0.5|p|^2 - 0.5|q|^2 = -0.5 d^2 <= 0.
// rm folds t = p.q + wq over cols (wp added in epilogue: max u = max t + wp).
// col-min d^2 <-> col-max u (LDS ds_min on bit patterns).
// float-max over non-positive floats == uint-min over bit patterns (exact).
__global__ __launch_bounds__(THREADS) void cd_both_kernel(
    const float* __restrict__ pred, const float* __restrict__ gt,
    const float* __restrict__ coords,
    unsigned int* __restrict__ min1, unsigned int* __restrict__ min2)
{
    __shared__ float4 s4[COLB];           // (x, y, z, wq=-0.5|q|^2)
    __shared__ unsigned int colm[COLB];   // bits of col-max u

    int bid = blockIdx.x;
    int cb = bid & (NCB - 1);
    int pb = (bid >> 6) & (PB - 1);
    int b  = bid >> 8;

    const float* cbase = coords + b * 3 * NN;
    const float* gbase = gt   + b * 3 * NN;   // rows: gt  -> min1
    const float* pbase = pred + b * 3 * NN;   // cols: gen -> min2

    // stage 128 cols + init colm (one barrier)
    if (threadIdx.x < COLB) {
        int n = cb * COLB + threadIdx.x;
        float x = cbase[0 * NN + n] + pbase[0 * NN + n];
        float y = cbase[1 * NN + n] + pbase[1 * NN + n];
        float z = cbase[2 * NN + n] + pbase[2 * NN + n];
        float w = -0.5f * fmaf(x, x, fmaf(y, y, z * z));
        s4[threadIdx.x] = make_float4(x, y, z, w);
        colm[threadIdx.x] = 0xFF800000u;  // -inf bits (umin identity)
    }

    // rows into registers
    int r0 = pb * ROWB;
    float px0,px1,px2,px3,px4,px5,px6,px7;
    float py0,py1,py2,py3,py4,py5,py6,py7;
    float pz0,pz1,pz2,pz3,pz4,pz5,pz6,pz7;
    float wp0,wp1,wp2,wp3,wp4,wp5,wp6,wp7;
    float rm0,rm1,rm2,rm3,rm4,rm5,rm6,rm7;
#define LOADROW(i) { int n = r0 + threadIdx.x + (i) * THREADS;            \
    float x = cbase[0*NN+n] + gbase[0*NN+n];                              \
    float y = cbase[1*NN+n] + gbase[1*NN+n];                              \
    float z = cbase[2*NN+n] + gbase[2*NN+n];                              \
    px##i = x; py##i = y; pz##i = z;                                      \
    wp##i = -0.5f * fmaf(x, x, fmaf(y, y, z * z));                        \
    rm##i = -3.0e38f; }
    LOADROW(0) LOADROW(1) LOADROW(2) LOADROW(3)
    LOADROW(4) LOADROW(5) LOADROW(6) LOADROW(7)
#undef LOADROW

    __syncthreads();

    // 64 column-pairs, lane-rotated; 1-ahead prefetch (A/B reg sets via unroll 2)
#define BODY(PR, QA, QB) {                                                 \
    float ta0,ta1,ta2,ta3,ta4,ta5,ta6,ta7;                                 \
    float tb0,tb1,tb2,tb3,tb4,tb5,tb6,tb7;                                 \
    ta0=fmaf(px0,(QA).x,(QA).w); ta1=fmaf(px1,(QA).x,(QA).w);              \
    ta2=fmaf(px2,(QA).x,(QA).w); ta3=fmaf(px3,(QA).x,(QA).w);              \
    ta4=fmaf(px4,(QA).x,(QA).w); ta5=fmaf(px5,(QA).x,(QA).w);              \
    ta6=fmaf(px6,(QA).x,(QA).w); ta7=fmaf(px7,(QA).x,(QA).w);              \
    ta0=fmaf(py0,(QA).y,ta0); ta1=fmaf(py1,(QA).y,ta1);                    \
    ta2=fmaf(py2,(QA).y,ta2); ta3=fmaf(py3,(QA).y,ta3);                    \
    ta4=fmaf(py4,(QA).y,ta4); ta5=fmaf(py5,(QA).y,ta5);                    \
    ta6=fmaf(py6,(QA).y,ta6); ta7=fmaf(py7,(QA).y,ta7);                    \
    ta0=fmaf(pz0,(QA).z,ta0); ta1=fmaf(pz1,(QA).z,ta1);                    \
    ta2=fmaf(pz2,(QA).z,ta2); ta3=fmaf(pz3,(QA).z,ta3);                    \
    ta4=fmaf(pz4,(QA).z,ta4); ta5=fmaf(pz5,(QA).z,ta5);                    \
    ta6=fmaf(pz6,(QA).z,ta6); ta7=fmaf(pz7,(QA).z,ta7);                    \
    tb0=fmaf(px0,(QB).x,(QB).w); tb1=fmaf(px1,(QB).x,(QB).w);              \
    tb2=fmaf(px2,(QB).x,(QB).w); tb3=fmaf(px3,(QB).x,(QB).w);              \
    tb4=fmaf(px4,(QB).x,(QB).w); tb5=fmaf(px5,(QB).x,(QB).w);              \
    tb6=fmaf(px6,(QB).x,(QB).w); tb7=fmaf(px7,(QB).x,(QB).w);              \
    tb0=fmaf(py0,(QB).y,tb0); tb1=fmaf(py1,(QB).y,tb1);                    \
    tb2=fmaf(py2,(QB).y,tb2); tb3=fmaf(py3,(QB).y,tb3);                    \
    tb4=fmaf(py4,(QB).y,tb4); tb5=fmaf(py5,(QB).y,tb5);                    \
    tb6=fmaf(py6,(QB).y,tb6); tb7=fmaf(py7,(QB).y,tb7);                    \
    tb0=fmaf(pz0,(QB).z,tb0); tb1=fmaf(pz1,(QB).z,tb1);                    \
    tb2=fmaf(pz2,(QB).z,tb2); tb3=fmaf(pz3,(QB).z,tb3);                    \
    tb4=fmaf(pz4,(QB).z,tb4); tb5=fmaf(pz5,(QB).z,tb5);                    \
    tb6=fmaf(pz6,(QB).z,tb6); tb7=fmaf(pz7,(QB).z,tb7);                    \
    rm0=max3f(rm0,ta0,tb0); rm1=max3f(rm1,ta1,tb1);                        \
    rm2=max3f(rm2,ta2,tb2); rm3=max3f(rm3,ta3,tb3);                        \
    rm4=max3f(rm4,ta4,tb4); rm5=max3f(rm5,ta5,tb5);                        \
    rm6=max3f(rm6,ta6,tb6); rm7=max3f(rm7,ta7,tb7);                        \
    ta0+=wp0; ta1+=wp1; ta2+=wp2; ta3+=wp3;                                \
    ta4+=wp4; ta5+=wp5; ta6+=wp6; ta7+=wp7;                                \
    float sA = max3f(max3f(ta0,ta1,ta2), max3f(ta3,ta4,ta5),               \
                     fmaxf(ta6,ta7));                                      \
    tb0+=wp0; tb1+=wp1; tb2+=wp2; tb3+=wp3;                                \
    tb4+=wp4; tb5+=wp5; tb6+=wp6; tb7+=wp7;                                \
    float sB = max3f(max3f(tb0,tb1,tb2), max3f(tb3,tb4,tb5),               \
                     fmaxf(tb6,tb7));                                      \
    atomicMin(&colm[2*(PR)],     __float_as_uint(sA));                     \
    atomicMin(&colm[2*(PR)+1],   __float_as_uint(sB));                     \
}

    int pr = threadIdx.x & 63;
    float4 qa = s4[2*pr], qb = s4[2*pr+1];
#pragma unroll 2
    for (int m = 1; m <= 64; ++m) {
        int prn = (threadIdx.x + m) & 63;
        float4 na = s4[2*prn], nb = s4[2*prn+1];   // prefetch (last wraps, harmless)
        BODY(pr, qa, qb);
        pr = prn; qa = na; qb = nb;
    }
#undef BODY

    // row epilogue: max u = rm + wp ; d^2 = -2*(rm+wp), clamp >= 0
#define ROWEP(i) { float d = fmaxf(-2.0f * (rm##i + wp##i), 0.0f);         \
    int n = r0 + threadIdx.x + (i) * THREADS;                              \
    atomicMin(&min1[b * NN + n], __float_as_uint(d)); }
    ROWEP(0) ROWEP(1) ROWEP(2) ROWEP(3) ROWEP(4) ROWEP(5) ROWEP(6) ROWEP(7)
#undef ROWEP

    __syncthreads();   // drain ds_min before reading colm
    if (threadIdx.x < COLB) {
        float u = __uint_as_float(colm[threadIdx.x]);
        float d = fmaxf(-2.0f * u, 0.0f);
        atomicMin(&min2[b * NN + cb * COLB + threadIdx.x], __float_as_uint(d));
    }
}

__global__ __launch_bounds__(1024) void cd_reduce_kernel(const unsigned int* __restrict__ mins,
                                                         float* __restrict__ out)
{
    // one block, 1024 threads, 65536 values
    float s = 0.0f;
    for (int k = 0; k < 2 * BB * NN / 1024; ++k)
        s += __uint_as_float(mins[threadIdx.x + k * 1024]);
#pragma unroll
    for (int off = 32; off > 0; off >>= 1)
        s += __shfl_down(s, off, 64);
    __shared__ float wsum[16];
    int wave = threadIdx.x >> 6;
    if ((threadIdx.x & 63) == 0) wsum[wave] = s;
    __syncthreads();
    if (threadIdx.x == 0) {
        float t = 0.0f;
#pragma unroll
        for (int w = 0; w < 16; ++w) t += wsum[w];
        out[0] = t / (float)BB;
    }
}

extern "C" void kernel_launch(void* const* d_in, const int* in_sizes, int n_in,
                              void* d_out, int out_size, void* d_ws, size_t ws_size,
                              hipStream_t stream) {
    const float* pred   = (const float*)d_in[0];
    const float* gt     = (const float*)d_in[1];
    const float* coords = (const float*)d_in[2];
    float* out = (float*)d_out;

    unsigned int* mins = (unsigned int*)d_ws;       // min1[BB*NN] then min2[BB*NN]
    unsigned int* min1 = mins;
    unsigned int* min2 = mins + BB * NN;

    int total_mins = 2 * BB * NN;                   // 65536
    hipLaunchKernelGGL(cd_init_kernel, dim3(total_mins / 256), dim3(256), 0, stream,
                       mins, total_mins);

    int nblocks = BB * PB * NCB;                    // 1024
    hipLaunchKernelGGL(cd_both_kernel, dim3(nblocks), dim3(THREADS), 0, stream,
                       pred, gt, coords, min1, min2);

    hipLaunchKernelGGL(cd_reduce_kernel, dim3(1), dim3(1024), 0, stream, mins, out);
}

// Round 9
// 44.063 us; speedup vs baseline: 2.9926x; 1.0150x over previous
//
#include <hip/hip_runtime.h>

#define BB 4
#define NN 8192
#define RI 8                   // rows per thread
#define THREADS 256
#define ROWB (THREADS * RI)    // 2048 rows per block
#define PB (NN / ROWB)         // 4 row-blocks
#define COLB 128               // cols per block (staged once)
#define NCB (NN / COLB)        // 64 col-blocks

__device__ inline float max3f(float a, float b, float c) {
    float d;
    asm("v_max3_f32 %0, %1, %2, %3" : "=v"(d) : "v"(a), "v"(b), "v"(c));
    return d;
}

__global__ void cd_init_kernel(unsigned int* mins, int n) {
    int i = blockIdx.x * blockDim.x + threadIdx.x;
    if (i < n) mins[i] = 0x7F800000u;  // +inf
}

// u = p.q - 0.5|p|^2 - 0.5|q|^2 = -0.5 d^2 <= 0.
// rm folds t = p.q + wq over cols (wp added back in row epilogue).
// col-min d^2 <-> col-max u (LDS ds_min on bit patterns).
// float-max over non-positive floats == uint-min over bit patterns (exact).
__global__ __launch_bounds__(THREADS) void cd_both_kernel(
    const float* __restrict__ pred, const float* __restrict__ gt,
    const float* __restrict__ coords,
    unsigned int* __restrict__ min1, unsigned int* __restrict__ min2)
{
    __shared__ float4 sA[COLB / 2];       // even cols 2p: (x,y,z,wq)
    __shared__ float4 sB[COLB / 2];       // odd  cols 2p+1
    __shared__ unsigned int colm[COLB];   // bits of col-max u

    int bid = blockIdx.x;
    int cb = bid & (NCB - 1);
    int pb = (bid >> 6) & (PB - 1);
    int b  = bid >> 8;

    const float* cbase = coords + b * 3 * NN;
    const float* gbase = gt   + b * 3 * NN;   // rows: gt  -> min1
    const float* pbase = pred + b * 3 * NN;   // cols: gen -> min2

    // stage 128 cols into split arrays + init colm (one barrier)
    if (threadIdx.x < COLB) {
        int c = threadIdx.x;
        int n = cb * COLB + c;
        float x = cbase[0 * NN + n] + pbase[0 * NN + n];
        float y = cbase[1 * NN + n] + pbase[1 * NN + n];
        float z = cbase[2 * NN + n] + pbase[2 * NN + n];
        float w = -0.5f * fmaf(x, x, fmaf(y, y, z * z));
        float4 v = make_float4(x, y, z, w);
        if (c & 1) sB[c >> 1] = v; else sA[c >> 1] = v;
        colm[c] = 0xFF800000u;  // -inf bits (umin identity)
    }

    // rows into registers
    int r0 = pb * ROWB;
    float px0,px1,px2,px3,px4,px5,px6,px7;
    float py0,py1,py2,py3,py4,py5,py6,py7;
    float pz0,pz1,pz2,pz3,pz4,pz5,pz6,pz7;
    float wp0,wp1,wp2,wp3,wp4,wp5,wp6,wp7;
    float rm0,rm1,rm2,rm3,rm4,rm5,rm6,rm7;
#define LOADROW(i) { int n = r0 + threadIdx.x + (i) * THREADS;            \
    float x = cbase[0*NN+n] + gbase[0*NN+n];                              \
    float y = cbase[1*NN+n] + gbase[1*NN+n];                              \
    float z = cbase[2*NN+n] + gbase[2*NN+n];                              \
    px##i = x; py##i = y; pz##i = z;                                      \
    wp##i = -0.5f * fmaf(x, x, fmaf(y, y, z * z));                        \
    rm##i = -3.0e38f; }
    LOADROW(0) LOADROW(1) LOADROW(2) LOADROW(3)
    LOADROW(4) LOADROW(5) LOADROW(6) LOADROW(7)
#undef LOADROW

    __syncthreads();

    // 64 column-pairs, lane-staggered start, manual 2-phase (no reg rotation)
#define BODY(P, QA, QB) {                                                  \
    float ta0,ta1,ta2,ta3,ta4,ta5,ta6,ta7;                                 \
    float tb0,tb1,tb2,tb3,tb4,tb5,tb6,tb7;                                 \
    ta0=fmaf(px0,(QA).x,(QA).w); ta1=fmaf(px1,(QA).x,(QA).w);              \
    ta2=fmaf(px2,(QA).x,(QA).w); ta3=fmaf(px3,(QA).x,(QA).w);              \
    ta4=fmaf(px4,(QA).x,(QA).w); ta5=fmaf(px5,(QA).x,(QA).w);              \
    ta6=fmaf(px6,(QA).x,(QA).w); ta7=fmaf(px7,(QA).x,(QA).w);              \
    ta0=fmaf(py0,(QA).y,ta0); ta1=fmaf(py1,(QA).y,ta1);                    \
    ta2=fmaf(py2,(QA).y,ta2); ta3=fmaf(py3,(QA).y,ta3);                    \
    ta4=fmaf(py4,(QA).y,ta4); ta5=fmaf(py5,(QA).y,ta5);                    \
    ta6=fmaf(py6,(QA).y,ta6); ta7=fmaf(py7,(QA).y,ta7);                    \
    ta0=fmaf(pz0,(QA).z,ta0); ta1=fmaf(pz1,(QA).z,ta1);                    \
    ta2=fmaf(pz2,(QA).z,ta2); ta3=fmaf(pz3,(QA).z,ta3);                    \
    ta4=fmaf(pz4,(QA).z,ta4); ta5=fmaf(pz5,(QA).z,ta5);                    \
    ta6=fmaf(pz6,(QA).z,ta6); ta7=fmaf(pz7,(QA).z,ta7);                    \
    tb0=fmaf(px0,(QB).x,(QB).w); tb1=fmaf(px1,(QB).x,(QB).w);              \
    tb2=fmaf(px2,(QB).x,(QB).w); tb3=fmaf(px3,(QB).x,(QB).w);              \
    tb4=fmaf(px4,(QB).x,(QB).w); tb5=fmaf(px5,(QB).x,(QB).w);              \
    tb6=fmaf(px6,(QB).x,(QB).w); tb7=fmaf(px7,(QB).x,(QB).w);              \
    tb0=fmaf(py0,(QB).y,tb0); tb1=fmaf(py1,(QB).y,tb1);                    \
    tb2=fmaf(py2,(QB).y,tb2); tb3=fmaf(py3,(QB).y,tb3);                    \
    tb4=fmaf(py4,(QB).y,tb4); tb5=fmaf(py5,(QB).y,tb5);                    \
    tb6=fmaf(py6,(QB).y,tb6); tb7=fmaf(py7,(QB).y,tb7);                    \
    tb0=fmaf(pz0,(QB).z,tb0); tb1=fmaf(pz1,(QB).z,tb1);                    \
    tb2=fmaf(pz2,(QB).z,tb2); tb3=fmaf(pz3,(QB).z,tb3);                    \
    tb4=fmaf(pz4,(QB).z,tb4); tb5=fmaf(pz5,(QB).z,tb5);                    \
    tb6=fmaf(pz6,(QB).z,tb6); tb7=fmaf(pz7,(QB).z,tb7);                    \
    rm0=max3f(rm0,ta0,tb0); rm1=max3f(rm1,ta1,tb1);                        \
    rm2=max3f(rm2,ta2,tb2); rm3=max3f(rm3,ta3,tb3);                        \
    rm4=max3f(rm4,ta4,tb4); rm5=max3f(rm5,ta5,tb5);                        \
    rm6=max3f(rm6,ta6,tb6); rm7=max3f(rm7,ta7,tb7);                        \
    ta0+=wp0; ta1+=wp1; ta2+=wp2; ta3+=wp3;                                \
    ta4+=wp4; ta5+=wp5; ta6+=wp6; ta7+=wp7;                                \
    float sAv = max3f(max3f(ta0,ta1,ta2), max3f(ta3,ta4,ta5),              \
                      fmaxf(ta6,ta7));                                     \
    tb0+=wp0; tb1+=wp1; tb2+=wp2; tb3+=wp3;                                \
    tb4+=wp4; tb5+=wp5; tb6+=wp6; tb7+=wp7;                                \
    float sBv = max3f(max3f(tb0,tb1,tb2), max3f(tb3,tb4,tb5),              \
                      fmaxf(tb6,tb7));                                     \
    atomicMin(&colm[2*(P)],   __float_as_uint(sAv));                       \
    atomicMin(&colm[2*(P)+1], __float_as_uint(sBv));                       \
}

    {
        int pA = threadIdx.x & 63;
        float4 a0 = sA[pA], b0 = sB[pA];
#pragma unroll 4
        for (int m = 0; m < 64; m += 2) {
            int pB = (pA + 1) & 63;
            float4 a1 = sA[pB], b1 = sB[pB];   // prefetch for phase 2
            BODY(pA, a0, b0);
            int pC = (pB + 1) & 63;
            a0 = sA[pC]; b0 = sB[pC];          // prefetch for next phase 1
            BODY(pB, a1, b1);
            pA = pC;
        }
    }
#undef BODY

    // row epilogue: max u = rm + wp ; d^2 = -2*(rm+wp), clamp >= 0
#define ROWEP(i) { float d = fmaxf(-2.0f * (rm##i + wp##i), 0.0f);         \
    int n = r0 + threadIdx.x + (i) * THREADS;                              \
    atomicMin(&min1[b * NN + n], __float_as_uint(d)); }
    ROWEP(0) ROWEP(1) ROWEP(2) ROWEP(3) ROWEP(4) ROWEP(5) ROWEP(6) ROWEP(7)
#undef ROWEP

    __syncthreads();   // drain ds_min before reading colm
    if (threadIdx.x < COLB) {
        float u = __uint_as_float(colm[threadIdx.x]);
        float d = fmaxf(-2.0f * u, 0.0f);
        atomicMin(&min2[b * NN + cb * COLB + threadIdx.x], __float_as_uint(d));
    }
}

__global__ __launch_bounds__(1024) void cd_reduce_kernel(const unsigned int* __restrict__ mins,
                                                         float* __restrict__ out)
{
    // one block, 1024 threads, 65536 values
    float s = 0.0f;
    for (int k = 0; k < 2 * BB * NN / 1024; ++k)
        s += __uint_as_float(mins[threadIdx.x + k * 1024]);
#pragma unroll
    for (int off = 32; off > 0; off >>= 1)
        s += __shfl_down(s, off, 64);
    __shared__ float wsum[16];
    int wave = threadIdx.x >> 6;
    if ((threadIdx.x & 63) == 0) wsum[wave] = s;
    __syncthreads();
    if (threadIdx.x == 0) {
        float t = 0.0f;
#pragma unroll
        for (int w = 0; w < 16; ++w) t += wsum[w];
        out[0] = t / (float)BB;
    }
}

extern "C" void kernel_launch(void* const* d_in, const int* in_sizes, int n_in,
                              void* d_out, int out_size, void* d_ws, size_t ws_size,
                              hipStream_t stream) {
    const float* pred   = (const float*)d_in[0];
    const float* gt     = (const float*)d_in[1];
    const float* coords = (const float*)d_in[2];
    float* out = (float*)d_out;

    unsigned int* mins = (unsigned int*)d_ws;       // min1[BB*NN] then min2[BB*NN]
    unsigned int* min1 = mins;
    unsigned int* min2 = mins + BB * NN;

    int total_mins = 2 * BB * NN;                   // 65536
    hipLaunchKernelGGL(cd_init_kernel, dim3(total_mins / 256), dim3(256), 0, stream,
                       mins, total_mins);

    int nblocks = BB * PB * NCB;                    // 1024
    hipLaunchKernelGGL(cd_both_kernel, dim3(nblocks), dim3(THREADS), 0, stream,
                       pred, gt, coords, min1, min2);

    hipLaunchKernelGGL(cd_reduce_kernel, dim3(1), dim3(1024), 0, stream, mins, out);
}